// Round 3
// baseline (123.295 us; speedup 1.0000x reference)
//
#include <hip/hip_runtime.h>

typedef short bf16x8 __attribute__((ext_vector_type(8)));   // 8 bf16 in 4 VGPRs
typedef float f32x4v __attribute__((ext_vector_type(4)));

// ---- constants derived from the reference ----
// grid = linspace(-1,1,12); centers c_k = -1 + (3+k)*2/11, k=0..7
// h = 0.4 + 1e-6 ; z_k = (x - c_k)/h = u - k*DLT,  u = (x - c0)/h
// basis_k = exp(-z_k^2/2) = exp2(A2*u^2) * exp2(B2*u)^k * exp2(GCF*k^2)
// exp2(GCF*k^2) is constant per k and folded into the weights at prep time.
constexpr double H_D    = 0.4 + 1e-6;
constexpr double INVH_D = 1.0 / H_D;
constexpr double C0_D   = -1.0 + 6.0 / 11.0;
constexpr double DLT_D  = (2.0 / 11.0) / H_D;
constexpr double L2E_D  = 1.4426950408889634;

constexpr float INVH = (float)INVH_D;
constexpr float NC0H = (float)(-C0_D * INVH_D);           // u = x*INVH + NC0H
constexpr float A2f  = (float)(-0.5 * L2E_D);             // E0 = exp2(A2*u*u)
constexpr float B2f  = (float)(DLT_D * L2E_D);            // r  = exp2(B2*u)
constexpr float GCF  = (float)(-0.5 * DLT_D * DLT_D * L2E_D); // g_k = exp2(GCF*k*k)
constexpr float NL2E = (float)(-L2E_D);

__device__ __forceinline__ float fexp2(float v) {
#if __has_builtin(__builtin_amdgcn_exp2f)
  return __builtin_amdgcn_exp2f(v);
#else
  return exp2f(v);
#endif
}
__device__ __forceinline__ float frcp(float v) {
#if __has_builtin(__builtin_amdgcn_rcpf)
  return __builtin_amdgcn_rcpf(v);
#else
  return 1.0f / v;
#endif
}
__device__ __forceinline__ float siluf(float v) {
  // v * sigmoid(v) = v / (1 + 2^(-log2e * v))
  return v * frcp(1.0f + fexp2(NL2E * v));
}
// pack two fp32 -> one dword of two bf16 (round-half-up), via v_perm_b32
__device__ __forceinline__ unsigned pk2(float lo, float hi) {
  unsigned a = __float_as_uint(hi) + 0x8000u;
  unsigned b = __float_as_uint(lo) + 0x8000u;
  return __builtin_amdgcn_perm(a, b, 0x07060302u); // [a.hi16 : b.hi16]
}
__device__ __forceinline__ bf16x8 packfrag(const float (&v)[8]) {
  uint4 d;
  d.x = pk2(v[0], v[1]);
  d.y = pk2(v[2], v[3]);
  d.z = pk2(v[4], v[5]);
  d.w = pk2(v[6], v[7]);
  return __builtin_bit_cast(bf16x8, d);
}
// RNE fp32 -> bf16 (prep path)
__device__ __forceinline__ unsigned rne16(float f) {
  unsigned u = __float_as_uint(f);
  return (u + 0x7fffu + ((u >> 16) & 1u)) >> 16;
}

// ---------------- prep: build fragment-ordered bf16 weights + bias ----------------
// K ordering: k = G*288 + t*32 + c   (G=0..3 channel-groups of 32, t=0..8 feature,
//                                     c = quad*8 + j channel within group)
// Fragment entry e = (G*9+t)*2 + h  (h = column half), lane l: col n = h*16 + (l&15),
// channels cbase = G*32 + (l>>4)*8 + (0..7)  -> matches MFMA B[k=quad*8+j][n=lane&15].
__global__ void kan_prep(const float* __restrict__ coeff,
                         const float* __restrict__ bw,
                         const float* __restrict__ bb,
                         const float* __restrict__ ew,
                         uint4* __restrict__ wfrag,
                         float* __restrict__ bias) {
  if (blockIdx.x == 18) {
    int n = threadIdx.x;
    if (n < 32) {
      float s = 0.f;
      for (int i = 0; i < 128; ++i) s += ew[i * 32 + n] * bb[i * 32 + n];
      bias[n] = s;
    }
    return;
  }
  const int e    = blockIdx.x * 4 + (threadIdx.x >> 6); // 0..71  (= s*2 + h)
  const int lane = threadIdx.x & 63;
  const int s = e >> 1, h = e & 1;
  const int G = s / 9, t = s % 9;
  const int n = h * 16 + (lane & 15);
  const int cbase = G * 32 + (lane >> 4) * 8;
  float v[8];
  if (t == 0) {
#pragma unroll
    for (int j = 0; j < 8; ++j) {
      int i = cbase + j;
      v[j] = ew[i * 32 + n] * bw[i * 32 + n];
    }
  } else {
    const int k = t - 1;
    const float g = exp2f(GCF * (float)(k * k)); // fold g_k into weight
#pragma unroll
    for (int j = 0; j < 8; ++j) {
      int i = cbase + j;
      v[j] = ew[i * 32 + n] * coeff[(i * 32 + n) * 8 + k] * g;
    }
  }
  uint4 d;
  d.x = (rne16(v[1]) << 16) | rne16(v[0]);
  d.y = (rne16(v[3]) << 16) | rne16(v[2]);
  d.z = (rne16(v[5]) << 16) | rne16(v[4]);
  d.w = (rne16(v[7]) << 16) | rne16(v[6]);
  wfrag[e * 64 + lane] = d;
}

__device__ __forceinline__ void load_x8(float (&xb)[2][8],
                                        const float* __restrict__ xbase,
                                        int coloff) {
#pragma unroll
  for (int tl = 0; tl < 2; ++tl) {
    const float4* p =
        reinterpret_cast<const float4*>(xbase + (long)tl * 16 * 128 + coloff);
    float4 a = p[0], b = p[1];
    xb[tl][0] = a.x; xb[tl][1] = a.y; xb[tl][2] = a.z; xb[tl][3] = a.w;
    xb[tl][4] = b.x; xb[tl][5] = b.y; xb[tl][6] = b.z; xb[tl][7] = b.w;
  }
}

// ---------------- main: fused feature-gen + MFMA GEMM ----------------
// Each wave: 2 tiles of 16 rows (32 rows), full K=1152, N=32 (two 16-col halves).
// G-loop and t-loop are ROLLED (unroll 1) with a 1-deep weight double-buffer so
// live VGPRs stay under the 128 cap of __launch_bounds__(256,4) — no spills.
__global__ __launch_bounds__(256, 4) void kan_main(
    const float* __restrict__ x,
    const uint4* __restrict__ wfrag,
    const float* __restrict__ bias,
    float* __restrict__ out) {
  const int lane = threadIdx.x & 63;
  const int wave = threadIdx.x >> 6;
  const int m    = lane & 15;  // A row-in-tile; also C/D column (within half)
  const int quad = lane >> 4;  // A channel-octet selector; C/D row group
  const long rowbase = ((long)blockIdx.x * 4 + wave) * 32;

  f32x4v acc[2][2];
#pragma unroll
  for (int tl = 0; tl < 2; ++tl)
#pragma unroll
    for (int hh = 0; hh < 2; ++hh)
#pragma unroll
      for (int rr = 0; rr < 4; ++rr) acc[tl][hh][rr] = 0.f;

  // per-lane x base: row (rowbase + tl*16 + m), octet quad*8, group G*32
  const float* xbase = x + (rowbase + m) * 128 + (long)quad * 8;

  float xb[2][8];
  load_x8(xb, xbase, 0);

  const uint4* wf = wfrag + lane;

#pragma unroll 1
  for (int G = 0; G < 4; ++G) {
    // issue t=0 and t=1 weight loads early; latency hides under feature math
    uint4 wb0 = wf[0];
    uint4 wb1 = wf[64];
    uint4 wc0 = wf[128];
    uint4 wc1 = wf[192];

    // ---- consume xb into compact per-G state ----
    bf16x8 af0[2];
    float pg[2][8], rg[2][8];
#pragma unroll
    for (int tl = 0; tl < 2; ++tl) {
      float sv[8];
#pragma unroll
      for (int j = 0; j < 8; ++j) sv[j] = siluf(xb[tl][j]);
      af0[tl] = packfrag(sv);
#pragma unroll
      for (int j = 0; j < 8; ++j) {
        float u = fmaf(xb[tl][j], INVH, NC0H);
        pg[tl][j] = fexp2(A2f * u * u);
        rg[tl][j] = fexp2(B2f * u);
      }
    }

    // ---- prefetch next G's x; latency overlaps the t-loop below ----
    if (G < 3) load_x8(xb, xbase, (G + 1) * 32);

    // ---- t = 0 : silu feature ----
#pragma unroll
    for (int tl = 0; tl < 2; ++tl) {
      acc[tl][0] = __builtin_amdgcn_mfma_f32_16x16x32_bf16(
          af0[tl], __builtin_bit_cast(bf16x8, wb0), acc[tl][0], 0, 0, 0);
      acc[tl][1] = __builtin_amdgcn_mfma_f32_16x16x32_bf16(
          af0[tl], __builtin_bit_cast(bf16x8, wb1), acc[tl][1], 0, 0, 0);
    }

    // ---- t = 1..8 : gaussian recurrence (g_k folded into weights) ----
#pragma unroll 1
    for (int t = 1; t <= 8; ++t) {
      // one-ahead prefetch (t=8 reads past this G's frags: harmless, in-ws)
      uint4 wn0 = wf[(t + 1) * 128];
      uint4 wn1 = wf[(t + 1) * 128 + 64];
      bf16x8 c0 = __builtin_bit_cast(bf16x8, wc0);
      bf16x8 c1 = __builtin_bit_cast(bf16x8, wc1);
#pragma unroll
      for (int tl = 0; tl < 2; ++tl) {
        bf16x8 af = packfrag(pg[tl]);
        acc[tl][0] = __builtin_amdgcn_mfma_f32_16x16x32_bf16(af, c0, acc[tl][0], 0, 0, 0);
        acc[tl][1] = __builtin_amdgcn_mfma_f32_16x16x32_bf16(af, c1, acc[tl][1], 0, 0, 0);
#pragma unroll
        for (int j = 0; j < 8; ++j) pg[tl][j] *= rg[tl][j];
      }
      wc0 = wn0;
      wc1 = wn1;
    }
    wf += 18 * 64;
  }

  // epilogue: C/D layout col = lane&15 (per half), row = quad*4 + reg
  const float bv0 = bias[m];
  const float bv1 = bias[m + 16];
#pragma unroll
  for (int tl = 0; tl < 2; ++tl) {
#pragma unroll
    for (int rr = 0; rr < 4; ++rr) {
      long row = rowbase + tl * 16 + quad * 4 + rr;
      out[row * 32 + m]      = acc[tl][0][rr] + bv0;
      out[row * 32 + m + 16] = acc[tl][1][rr] + bv1;
    }
  }
}

extern "C" void kernel_launch(void* const* d_in, const int* in_sizes, int n_in,
                              void* d_out, int out_size, void* d_ws, size_t ws_size,
                              hipStream_t stream) {
  const float* x     = (const float*)d_in[0]; // (131072,128)
  const float* coeff = (const float*)d_in[1]; // (128,32,8)
  const float* bw    = (const float*)d_in[2]; // (128,32)
  const float* bb    = (const float*)d_in[3]; // (128,32)
  const float* ew    = (const float*)d_in[4]; // (128,32)

  uint4* wfrag = (uint4*)d_ws;                       // 72*64*16 = 73728 B
  float* bias  = (float*)((char*)d_ws + 73728);      // 32 floats

  kan_prep<<<19, 256, 0, stream>>>(coeff, bw, bb, ew, wfrag, bias);
  kan_main<<<1024, 256, 0, stream>>>(x, wfrag, bias, (float*)d_out);
}

// Round 4
// 119.092 us; speedup vs baseline: 1.0353x; 1.0353x over previous
//
#include <hip/hip_runtime.h>

typedef short bf16x8 __attribute__((ext_vector_type(8)));   // 8 bf16 in 4 VGPRs
typedef float f32x4v __attribute__((ext_vector_type(4)));

// ---- constants derived from the reference ----
// grid = linspace(-1,1,12); centers c_k = -1 + (3+k)*2/11, k=0..7
// h = 0.4 + 1e-6 ; z_k = (x - c_k)/h = u - k*DLT,  u = (x - c0)/h
// basis_k = exp(-z_k^2/2) = exp2(A2*u^2) * exp2(B2*u)^k * exp2(GCF*k^2)
// exp2(GCF*k^2) is constant per k and folded into the weights at prep time.
constexpr double H_D    = 0.4 + 1e-6;
constexpr double INVH_D = 1.0 / H_D;
constexpr double C0_D   = -1.0 + 6.0 / 11.0;
constexpr double DLT_D  = (2.0 / 11.0) / H_D;
constexpr double L2E_D  = 1.4426950408889634;

constexpr float INVH = (float)INVH_D;
constexpr float NC0H = (float)(-C0_D * INVH_D);           // u = x*INVH + NC0H
constexpr float A2f  = (float)(-0.5 * L2E_D);             // E0 = exp2(A2*u*u)
constexpr float B2f  = (float)(DLT_D * L2E_D);            // r  = exp2(B2*u)
constexpr float GCF  = (float)(-0.5 * DLT_D * DLT_D * L2E_D); // g_k = exp2(GCF*k*k)
constexpr float NL2E = (float)(-L2E_D);

__device__ __forceinline__ float fexp2(float v) {
#if __has_builtin(__builtin_amdgcn_exp2f)
  return __builtin_amdgcn_exp2f(v);
#else
  return exp2f(v);
#endif
}
__device__ __forceinline__ float frcp(float v) {
#if __has_builtin(__builtin_amdgcn_rcpf)
  return __builtin_amdgcn_rcpf(v);
#else
  return 1.0f / v;
#endif
}
__device__ __forceinline__ float siluf(float v) {
  // v * sigmoid(v) = v / (1 + 2^(-log2e * v))
  return v * frcp(1.0f + fexp2(NL2E * v));
}
// pack two fp32 -> one dword of two bf16 (round-half-up), via v_perm_b32
__device__ __forceinline__ unsigned pk2(float lo, float hi) {
  unsigned a = __float_as_uint(hi) + 0x8000u;
  unsigned b = __float_as_uint(lo) + 0x8000u;
  return __builtin_amdgcn_perm(a, b, 0x07060302u); // [a.hi16 : b.hi16]
}
__device__ __forceinline__ bf16x8 packfrag(const float (&v)[8]) {
  uint4 d;
  d.x = pk2(v[0], v[1]);
  d.y = pk2(v[2], v[3]);
  d.z = pk2(v[4], v[5]);
  d.w = pk2(v[6], v[7]);
  return __builtin_bit_cast(bf16x8, d);
}
// RNE fp32 -> bf16 (prep path)
__device__ __forceinline__ unsigned rne16(float f) {
  unsigned u = __float_as_uint(f);
  return (u + 0x7fffu + ((u >> 16) & 1u)) >> 16;
}

// ---------------- prep: build fragment-ordered bf16 weights + bias ----------------
// K ordering: k = G*288 + t*32 + c   (G=0..3 channel-groups of 32, t=0..8 feature,
//                                     c = quad*8 + j channel within group)
// Fragment entry e = (G*9+t)*2 + h  (h = column half), lane l: col n = h*16 + (l&15),
// channels cbase = G*32 + (l>>4)*8 + (0..7)  -> matches MFMA B[k=quad*8+j][n=lane&15].
__global__ void kan_prep(const float* __restrict__ coeff,
                         const float* __restrict__ bw,
                         const float* __restrict__ bb,
                         const float* __restrict__ ew,
                         uint4* __restrict__ wfrag,
                         float* __restrict__ bias) {
  if (blockIdx.x == 18) {
    // bias[n] = sum_i ew[i][n]*bb[i][n]; 256 thr = 32 n × 8 chunks of 16 i
    __shared__ float part[256];
    const int n = threadIdx.x & 31;
    const int c = threadIdx.x >> 5;
    float s = 0.f;
#pragma unroll
    for (int i = c * 16; i < c * 16 + 16; ++i)
      s += ew[i * 32 + n] * bb[i * 32 + n];
    part[threadIdx.x] = s;
    __syncthreads();
    if (threadIdx.x < 32) {
      float t = 0.f;
#pragma unroll
      for (int c2 = 0; c2 < 8; ++c2) t += part[c2 * 32 + threadIdx.x];
      bias[threadIdx.x] = t;
    }
    return;
  }
  const int e    = blockIdx.x * 4 + (threadIdx.x >> 6); // 0..71  (= s*2 + h)
  const int lane = threadIdx.x & 63;
  const int s = e >> 1, h = e & 1;
  const int G = s / 9, t = s % 9;
  const int n = h * 16 + (lane & 15);
  const int cbase = G * 32 + (lane >> 4) * 8;
  float v[8];
  if (t == 0) {
#pragma unroll
    for (int j = 0; j < 8; ++j) {
      int i = cbase + j;
      v[j] = ew[i * 32 + n] * bw[i * 32 + n];
    }
  } else {
    const int k = t - 1;
    const float g = exp2f(GCF * (float)(k * k)); // fold g_k into weight
#pragma unroll
    for (int j = 0; j < 8; ++j) {
      int i = cbase + j;
      v[j] = ew[i * 32 + n] * coeff[(i * 32 + n) * 8 + k] * g;
    }
  }
  uint4 d;
  d.x = (rne16(v[1]) << 16) | rne16(v[0]);
  d.y = (rne16(v[3]) << 16) | rne16(v[2]);
  d.z = (rne16(v[5]) << 16) | rne16(v[4]);
  d.w = (rne16(v[7]) << 16) | rne16(v[6]);
  wfrag[e * 64 + lane] = d;
}

__device__ __forceinline__ void load_x8(float (&xb)[2][8],
                                        const float* __restrict__ xbase,
                                        int coloff) {
#pragma unroll
  for (int tl = 0; tl < 2; ++tl) {
    const float4* p =
        reinterpret_cast<const float4*>(xbase + (long)tl * 16 * 128 + coloff);
    float4 a = p[0], b = p[1];
    xb[tl][0] = a.x; xb[tl][1] = a.y; xb[tl][2] = a.z; xb[tl][3] = a.w;
    xb[tl][4] = b.x; xb[tl][5] = b.y; xb[tl][6] = b.z; xb[tl][7] = b.w;
  }
}

// ---------------- main: fused feature-gen + MFMA GEMM ----------------
// Each wave: 2 tiles of 16 rows (32 rows), full K=1152, N=32 (two 16-col halves).
// Weights are staged in LDS two G's at a time (36.9 KB; 4 blocks/CU) so the
// t-loop's weight reads ride lgkmcnt, fully decoupled from the x HBM prefetch
// on vmcnt (in-order vmcnt drain was serializing each G-body on x latency).
__global__ __launch_bounds__(256, 4) void kan_main(
    const float* __restrict__ x,
    const uint4* __restrict__ wfrag,
    const float* __restrict__ bias,
    float* __restrict__ out) {
  __shared__ uint4 wlds[38 * 64];  // 36*64 used (2 G's), 2*64 pad for prefetch overrun
  const int tid  = threadIdx.x;
  const int lane = tid & 63;
  const int wave = tid >> 6;
  const int m    = lane & 15;  // A row-in-tile; also C/D column (within half)
  const int quad = lane >> 4;  // A channel-octet selector; C/D row group
  const long rowbase = ((long)blockIdx.x * 4 + wave) * 32;

  f32x4v acc[2][2];
#pragma unroll
  for (int tl = 0; tl < 2; ++tl)
#pragma unroll
    for (int hh = 0; hh < 2; ++hh)
#pragma unroll
      for (int rr = 0; rr < 4; ++rr) acc[tl][hh][rr] = 0.f;

  // per-lane x base: row (rowbase + tl*16 + m), octet quad*8, group G*32
  const float* xbase = x + (rowbase + m) * 128 + (long)quad * 8;

  float xb[2][8];
  load_x8(xb, xbase, 0);   // G=0 x in flight (HBM) while we stage weights

  // stage phase 0: Gs {0,1} -> wlds[0..2303]
#pragma unroll
  for (int i = 0; i < 9; ++i) wlds[tid + i * 256] = wfrag[tid + i * 256];
  __syncthreads();

#pragma unroll 1
  for (int G = 0; G < 4; ++G) {
    if (G == 2) {
      __syncthreads();  // all reads of phase 0 done
#pragma unroll
      for (int i = 0; i < 9; ++i)
        wlds[tid + i * 256] = wfrag[36 * 64 + tid + i * 256];
      __syncthreads();
    }
    const uint4* wl = wlds + (G & 1) * 18 * 64 + lane;

    // issue t=0 / t=1 weight reads early (LDS, lgkmcnt)
    uint4 wb0 = wl[0];
    uint4 wb1 = wl[64];
    uint4 wc0 = wl[128];
    uint4 wc1 = wl[192];

    // ---- consume xb into compact per-G state ----
    bf16x8 af0[2];
    float pg[2][8], rg[2][8];
#pragma unroll
    for (int tl = 0; tl < 2; ++tl) {
      float sv[8];
#pragma unroll
      for (int j = 0; j < 8; ++j) sv[j] = siluf(xb[tl][j]);
      af0[tl] = packfrag(sv);
#pragma unroll
      for (int j = 0; j < 8; ++j) {
        float u = fmaf(xb[tl][j], INVH, NC0H);
        pg[tl][j] = fexp2(A2f * u * u);
        rg[tl][j] = fexp2(B2f * u);
      }
    }

    // ---- prefetch next G's x (vmcnt; consumed one full t-loop later) ----
    if (G < 3) load_x8(xb, xbase, (G + 1) * 32);

    // ---- t = 0 : silu feature ----
#pragma unroll
    for (int tl = 0; tl < 2; ++tl) {
      acc[tl][0] = __builtin_amdgcn_mfma_f32_16x16x32_bf16(
          af0[tl], __builtin_bit_cast(bf16x8, wb0), acc[tl][0], 0, 0, 0);
      acc[tl][1] = __builtin_amdgcn_mfma_f32_16x16x32_bf16(
          af0[tl], __builtin_bit_cast(bf16x8, wb1), acc[tl][1], 0, 0, 0);
    }

    // ---- t = 1..8 : gaussian recurrence (g_k folded into weights) ----
#pragma unroll 1
    for (int t = 1; t <= 8; ++t) {
      // one-ahead LDS prefetch (t=8 reads pad region: harmless, unused)
      uint4 wn0 = wl[(t + 1) * 128];
      uint4 wn1 = wl[(t + 1) * 128 + 64];
      bf16x8 c0 = __builtin_bit_cast(bf16x8, wc0);
      bf16x8 c1 = __builtin_bit_cast(bf16x8, wc1);
#pragma unroll
      for (int tl = 0; tl < 2; ++tl) {
        bf16x8 af = packfrag(pg[tl]);
        acc[tl][0] = __builtin_amdgcn_mfma_f32_16x16x32_bf16(af, c0, acc[tl][0], 0, 0, 0);
        acc[tl][1] = __builtin_amdgcn_mfma_f32_16x16x32_bf16(af, c1, acc[tl][1], 0, 0, 0);
#pragma unroll
        for (int j = 0; j < 8; ++j) pg[tl][j] *= rg[tl][j];
      }
      wc0 = wn0;
      wc1 = wn1;
    }
  }

  // epilogue: C/D layout col = lane&15 (per half), row = quad*4 + reg
  const float bv0 = bias[m];
  const float bv1 = bias[m + 16];
#pragma unroll
  for (int tl = 0; tl < 2; ++tl) {
#pragma unroll
    for (int rr = 0; rr < 4; ++rr) {
      long row = rowbase + tl * 16 + quad * 4 + rr;
      out[row * 32 + m]      = acc[tl][0][rr] + bv0;
      out[row * 32 + m + 16] = acc[tl][1][rr] + bv1;
    }
  }
}

extern "C" void kernel_launch(void* const* d_in, const int* in_sizes, int n_in,
                              void* d_out, int out_size, void* d_ws, size_t ws_size,
                              hipStream_t stream) {
  const float* x     = (const float*)d_in[0]; // (131072,128)
  const float* coeff = (const float*)d_in[1]; // (128,32,8)
  const float* bw    = (const float*)d_in[2]; // (128,32)
  const float* bb    = (const float*)d_in[3]; // (128,32)
  const float* ew    = (const float*)d_in[4]; // (128,32)

  uint4* wfrag = (uint4*)d_ws;                       // 72*64*16 = 73728 B
  float* bias  = (float*)((char*)d_ws + 73728);      // 32 floats

  kan_prep<<<19, 256, 0, stream>>>(coeff, bw, bb, ew, wfrag, bias);
  kan_main<<<1024, 256, 0, stream>>>(x, wfrag, bias, (float*)d_out);
}

// Round 5
// 116.272 us; speedup vs baseline: 1.0604x; 1.0243x over previous
//
#include <hip/hip_runtime.h>

typedef short bf16x8 __attribute__((ext_vector_type(8)));   // 8 bf16 in 4 VGPRs
typedef float f32x4v __attribute__((ext_vector_type(4)));

// ---- constants derived from the reference ----
// grid = linspace(-1,1,12); centers c_k = -1 + (3+k)*2/11, k=0..7
// h = 0.4 + 1e-6 ; z_k = (x - c_k)/h = u - k*DLT,  u = (x - c0)/h
// basis_k = exp(-z_k^2/2) = exp2(A2*u^2) * exp2(B2*u)^k * exp2(GCF*k^2)
// exp2(GCF*k^2) is constant per k and folded into the weights at prep time.
constexpr double H_D    = 0.4 + 1e-6;
constexpr double INVH_D = 1.0 / H_D;
constexpr double C0_D   = -1.0 + 6.0 / 11.0;
constexpr double DLT_D  = (2.0 / 11.0) / H_D;
constexpr double L2E_D  = 1.4426950408889634;

constexpr float INVH = (float)INVH_D;
constexpr float NC0H = (float)(-C0_D * INVH_D);           // u = x*INVH + NC0H
constexpr float A2f  = (float)(-0.5 * L2E_D);             // E0 = exp2(A2*u*u)
constexpr float B2f  = (float)(DLT_D * L2E_D);            // r  = exp2(B2*u)
constexpr float GCF  = (float)(-0.5 * DLT_D * DLT_D * L2E_D); // g_k = exp2(GCF*k*k)
constexpr float NL2E = (float)(-L2E_D);

__device__ __forceinline__ float fexp2(float v) {
#if __has_builtin(__builtin_amdgcn_exp2f)
  return __builtin_amdgcn_exp2f(v);
#else
  return exp2f(v);
#endif
}
__device__ __forceinline__ float frcp(float v) {
#if __has_builtin(__builtin_amdgcn_rcpf)
  return __builtin_amdgcn_rcpf(v);
#else
  return 1.0f / v;
#endif
}
__device__ __forceinline__ float siluf(float v) {
  // v * sigmoid(v) = v / (1 + 2^(-log2e * v))
  return v * frcp(1.0f + fexp2(NL2E * v));
}
// pack two fp32 -> one dword of two bf16 (round-half-up), via v_perm_b32
__device__ __forceinline__ unsigned pk2(float lo, float hi) {
  unsigned a = __float_as_uint(hi) + 0x8000u;
  unsigned b = __float_as_uint(lo) + 0x8000u;
  return __builtin_amdgcn_perm(a, b, 0x07060302u); // [a.hi16 : b.hi16]
}
__device__ __forceinline__ bf16x8 packfrag(const float (&v)[8]) {
  uint4 d;
  d.x = pk2(v[0], v[1]);
  d.y = pk2(v[2], v[3]);
  d.z = pk2(v[4], v[5]);
  d.w = pk2(v[6], v[7]);
  return __builtin_bit_cast(bf16x8, d);
}
// RNE fp32 -> bf16 (prep path)
__device__ __forceinline__ unsigned rne16(float f) {
  unsigned u = __float_as_uint(f);
  return (u + 0x7fffu + ((u >> 16) & 1u)) >> 16;
}

// ---------------- prep: build fragment-ordered bf16 weights + bias ----------------
// K ordering: k = G*288 + t*32 + c   (G=0..3 channel-groups of 32, t=0..8 feature,
//                                     c = quad*8 + j channel within group)
// Fragment entry e = (G*9+t)*2 + h  (h = column half), lane l: col n = h*16 + (l&15),
// channels cbase = G*32 + (l>>4)*8 + (0..7)  -> matches MFMA B[k=quad*8+j][n=lane&15].
__global__ void kan_prep(const float* __restrict__ coeff,
                         const float* __restrict__ bw,
                         const float* __restrict__ bb,
                         const float* __restrict__ ew,
                         uint4* __restrict__ wfrag,
                         float* __restrict__ bias) {
  if (blockIdx.x == 18) {
    // bias[n] = sum_i ew[i][n]*bb[i][n]; 256 thr = 32 n × 8 chunks of 16 i
    __shared__ float part[256];
    const int n = threadIdx.x & 31;
    const int c = threadIdx.x >> 5;
    float s = 0.f;
#pragma unroll
    for (int i = c * 16; i < c * 16 + 16; ++i)
      s += ew[i * 32 + n] * bb[i * 32 + n];
    part[threadIdx.x] = s;
    __syncthreads();
    if (threadIdx.x < 32) {
      float t = 0.f;
#pragma unroll
      for (int c2 = 0; c2 < 8; ++c2) t += part[c2 * 32 + threadIdx.x];
      bias[threadIdx.x] = t;
    }
    return;
  }
  const int e    = blockIdx.x * 4 + (threadIdx.x >> 6); // 0..71  (= s*2 + h)
  const int lane = threadIdx.x & 63;
  const int s = e >> 1, h = e & 1;
  const int G = s / 9, t = s % 9;
  const int n = h * 16 + (lane & 15);
  const int cbase = G * 32 + (lane >> 4) * 8;
  float v[8];
  if (t == 0) {
#pragma unroll
    for (int j = 0; j < 8; ++j) {
      int i = cbase + j;
      v[j] = ew[i * 32 + n] * bw[i * 32 + n];
    }
  } else {
    const int k = t - 1;
    const float g = exp2f(GCF * (float)(k * k)); // fold g_k into weight
#pragma unroll
    for (int j = 0; j < 8; ++j) {
      int i = cbase + j;
      v[j] = ew[i * 32 + n] * coeff[(i * 32 + n) * 8 + k] * g;
    }
  }
  uint4 d;
  d.x = (rne16(v[1]) << 16) | rne16(v[0]);
  d.y = (rne16(v[3]) << 16) | rne16(v[2]);
  d.z = (rne16(v[5]) << 16) | rne16(v[4]);
  d.w = (rne16(v[7]) << 16) | rne16(v[6]);
  wfrag[e * 64 + lane] = d;
}

// async global->LDS, 16B per lane; LDS layout must be base + lane*16 (it is:
// dest index = tid + i*256 -> per wave: wave-uniform base + lane*16).
__device__ __forceinline__ void gl_lds16(const uint4* g, uint4* l) {
  __builtin_amdgcn_global_load_lds(
      (const __attribute__((address_space(1))) void*)g,
      (__attribute__((address_space(3))) void*)l, 16, 0, 0);
}

// ---------------- main: fused feature-gen + MFMA GEMM ----------------
// 1 row-tile (16 rows) per wave, 256-thr blocks, 8 blocks/CU -> 32 waves/CU
// (100% occupancy target; VGPR capped at 64 by __launch_bounds__(256,8)).
// Weights staged per-G in LDS (18.4 KB) via global_load_lds width=16.
__global__ __launch_bounds__(256, 8) void kan_main(
    const float* __restrict__ x,
    const uint4* __restrict__ wfrag,
    const float* __restrict__ bias,
    float* __restrict__ out) {
  __shared__ uint4 wlds[1152];  // 18 fragment-entries * 64 lanes, one G
  const int tid  = threadIdx.x;
  const int lane = tid & 63;
  const int wave = tid >> 6;
  const int m    = lane & 15;  // A row-in-tile; also C/D column (within half)
  const int quad = lane >> 4;  // A channel-octet selector; C/D row group
  const long rowbase = ((long)blockIdx.x * 4 + wave) * 16;

  f32x4v acc0, acc1;
#pragma unroll
  for (int rr = 0; rr < 4; ++rr) { acc0[rr] = 0.f; acc1[rr] = 0.f; }

  // per-lane x base: row (rowbase + m), octet quad*8, group G*32
  const float* xbase = x + (rowbase + m) * 128 + (long)quad * 8;

  float xb[8];
  {
    const float4* p = reinterpret_cast<const float4*>(xbase);
    float4 a = p[0], b = p[1];
    xb[0] = a.x; xb[1] = a.y; xb[2] = a.z; xb[3] = a.w;
    xb[4] = b.x; xb[5] = b.y; xb[6] = b.z; xb[7] = b.w;
  }
  const float bv0 = bias[m];
  const float bv1 = bias[m + 16];

#pragma unroll 1
  for (int G = 0; G < 4; ++G) {
    if (G) __syncthreads();  // all LDS reads of previous G done
    // ---- stage G's 18 fragment entries (1152 uint4) into LDS ----
    const uint4* src = wfrag + (size_t)G * 1152;
#pragma unroll
    for (int i = 0; i < 4; ++i)
      gl_lds16(src + tid + i * 256, &wlds[tid + i * 256]);
    if (tid < 128) gl_lds16(src + 1024 + tid, &wlds[1024 + tid]);
    __syncthreads();  // drains vmcnt (staging + this G's x prefetch)

    // ---- consume xb into compact per-G state ----
    bf16x8 af0;
    float pg[8], rg[8];
    {
      float sv[8];
#pragma unroll
      for (int j = 0; j < 8; ++j) sv[j] = siluf(xb[j]);
      af0 = packfrag(sv);
#pragma unroll
      for (int j = 0; j < 8; ++j) {
        float u = fmaf(xb[j], INVH, NC0H);
        pg[j] = fexp2(A2f * u * u);
        rg[j] = fexp2(B2f * u);
      }
    }

    // ---- prefetch next G's x (vmcnt; consumed after next staging sync) ----
    if (G < 3) {
      const float4* p = reinterpret_cast<const float4*>(xbase + (G + 1) * 32);
      float4 a = p[0], b = p[1];
      xb[0] = a.x; xb[1] = a.y; xb[2] = a.z; xb[3] = a.w;
      xb[4] = b.x; xb[5] = b.y; xb[6] = b.z; xb[7] = b.w;
    }

    const uint4* wl = wlds + lane;

    // ---- t = 0 : silu feature ----
    acc0 = __builtin_amdgcn_mfma_f32_16x16x32_bf16(
        af0, __builtin_bit_cast(bf16x8, wl[0]), acc0, 0, 0, 0);
    acc1 = __builtin_amdgcn_mfma_f32_16x16x32_bf16(
        af0, __builtin_bit_cast(bf16x8, wl[64]), acc1, 0, 0, 0);

    // ---- t = 1..8 : gaussian recurrence (g_k folded into weights) ----
#pragma unroll
    for (int t = 1; t <= 8; ++t) {
      bf16x8 c0 = __builtin_bit_cast(bf16x8, wl[t * 128]);
      bf16x8 c1 = __builtin_bit_cast(bf16x8, wl[t * 128 + 64]);
      bf16x8 af = packfrag(pg);
      acc0 = __builtin_amdgcn_mfma_f32_16x16x32_bf16(af, c0, acc0, 0, 0, 0);
      acc1 = __builtin_amdgcn_mfma_f32_16x16x32_bf16(af, c1, acc1, 0, 0, 0);
      if (t < 8) {
#pragma unroll
        for (int j = 0; j < 8; ++j) pg[j] *= rg[j];
      }
    }
  }

  // epilogue: C/D layout col = lane&15 (per half), row = quad*4 + reg
#pragma unroll
  for (int rr = 0; rr < 4; ++rr) {
    long row = rowbase + quad * 4 + rr;
    out[row * 32 + m]      = acc0[rr] + bv0;
    out[row * 32 + m + 16] = acc1[rr] + bv1;
  }
}

extern "C" void kernel_launch(void* const* d_in, const int* in_sizes, int n_in,
                              void* d_out, int out_size, void* d_ws, size_t ws_size,
                              hipStream_t stream) {
  const float* x     = (const float*)d_in[0]; // (131072,128)
  const float* coeff = (const float*)d_in[1]; // (128,32,8)
  const float* bw    = (const float*)d_in[2]; // (128,32)
  const float* bb    = (const float*)d_in[3]; // (128,32)
  const float* ew    = (const float*)d_in[4]; // (128,32)

  uint4* wfrag = (uint4*)d_ws;                       // 72*64*16 = 73728 B
  float* bias  = (float*)((char*)d_ws + 73728);      // 32 floats

  kan_prep<<<19, 256, 0, stream>>>(coeff, bw, bb, ew, wfrag, bias);
  kan_main<<<2048, 256, 0, stream>>>(x, wfrag, bias, (float*)d_out);
}